// Round 4
// baseline (220.037 us; speedup 1.0000x reference)
//
#include <hip/hip_runtime.h>
#include <cstdint>
#include <cstddef>

// ---------------------------------------------------------------------------
// mask_moe: reproduce jax noisy-top-p gating bit-faithfully.
// PRNG: partitionable threefry (jax >= 0.4.36 default; gfx950-era jax is newer).
// Dots: f32, single accumulator, ascending-k fused FMA (hipBLASLt/Eigen order)
//   -- hypothesis: harness reference arithmetic is f32 sequential-k; our
//      earlier f64 dots flipped marginal rows (absmax 1.0 both rounds).
#define JAX_PARTITIONABLE 1
// ---------------------------------------------------------------------------

namespace {

constexpr int kBH = 256;                  // B*H
constexpr int kL = 512;                   // L
constexpr int kE = 3;                     // experts
constexpr int kRows = kBH * kL;           // 131072 gating rows
constexpr uint32_t kNoiseN = (uint32_t)kRows * kE;  // 393216 normal draws

__device__ __forceinline__ uint32_t rotl32(uint32_t v, int n) {
  return (v << n) | (v >> (32 - n));
}

// Threefry-2x32, 20 rounds, key = (0, 42)  [jax.random.key(42)]
__device__ __forceinline__ void threefry2x32_k42(uint32_t& x0, uint32_t& x1) {
  const uint32_t ks0 = 0u;
  const uint32_t ks1 = 42u;
  const uint32_t ks2 = 0u ^ 42u ^ 0x1BD11BDAu;
  x0 += ks0; x1 += ks1;
#define TF_ROUND(r) { x0 += x1; x1 = rotl32(x1, (r)); x1 ^= x0; }
  TF_ROUND(13) TF_ROUND(15) TF_ROUND(26) TF_ROUND(6)
  x0 += ks1; x1 += ks2 + 1u;
  TF_ROUND(17) TF_ROUND(29) TF_ROUND(16) TF_ROUND(24)
  x0 += ks2; x1 += ks0 + 2u;
  TF_ROUND(13) TF_ROUND(15) TF_ROUND(26) TF_ROUND(6)
  x0 += ks0; x1 += ks1 + 3u;
  TF_ROUND(17) TF_ROUND(29) TF_ROUND(16) TF_ROUND(24)
  x0 += ks1; x1 += ks2 + 4u;
  TF_ROUND(13) TF_ROUND(15) TF_ROUND(26) TF_ROUND(6)
  x0 += ks2; x1 += ks0 + 5u;
#undef TF_ROUND
}

__device__ __forceinline__ uint32_t jax_random_bits(uint32_t flat_idx) {
#if JAX_PARTITIONABLE
  // bits = x0 ^ x1 of threefry(key, (hi32(i), lo32(i))); i < 2^32 so hi = 0.
  uint32_t x0 = 0u;
  uint32_t x1 = flat_idx;
  threefry2x32_k42(x0, x1);
  return x0 ^ x1;
#else
  // legacy: counts = iota(N) split into halves (i, N/2 + i).
  const uint32_t half = kNoiseN / 2u;
  const bool second = flat_idx >= half;
  const uint32_t j = second ? (flat_idx - half) : flat_idx;
  uint32_t x0 = j;
  uint32_t x1 = half + j;
  threefry2x32_k42(x0, x1);
  return second ? x1 : x0;
#endif
}

// jax.random.normal f32: uniform(-0.99999994, 1.0) then sqrt(2)*erfinv (XLA Giles poly)
__device__ float bits_to_normal(uint32_t bits) {
#pragma clang fp contract(off)
  const uint32_t fb = (bits >> 9) | 0x3F800000u;
  const float f = __uint_as_float(fb) - 1.0f;   // [0, 1)
  const float lo = -0.99999994f;                 // nextafterf(-1, 0)
  float u = f * 2.0f + lo;                       // (maxval-minval) == 2.0f exactly
  u = fmaxf(lo, u);
  float w = -log1pf(-(u * u));
  float p;
  if (w < 5.0f) {
    w = w - 2.5f;
    p = 2.81022636e-08f;
    p = 3.43273939e-07f + p * w;
    p = -3.5233877e-06f + p * w;
    p = -4.39150654e-06f + p * w;
    p = 0.00021858087f + p * w;
    p = -0.00125372503f + p * w;
    p = -0.00417768164f + p * w;
    p = 0.246640727f + p * w;
    p = 1.50140941f + p * w;
  } else {
    w = sqrtf(w) - 3.0f;
    p = -0.000200214257f;
    p = 0.000100950558f + p * w;
    p = 0.00134934322f + p * w;
    p = -0.00367342844f + p * w;
    p = 0.00573950773f + p * w;
    p = -0.0076224613f + p * w;
    p = 0.00943887047f + p * w;
    p = 1.00167406f + p * w;
    p = 2.83297682f + p * w;
  }
  const float einv = p * u;
  return 1.41421354f * einv;  // f32(sqrt(2)) * erfinv(u)
}

// jax.nn.softplus(x) = logaddexp(x, 0) = max(x,0) + log1p(exp(-|x|))
__device__ __forceinline__ float softplus_f32(float v) {
#pragma clang fp contract(off)
  const float amax = fmaxf(v, 0.0f);
  return amax + log1pf(expf(-fabsf(v)));
}

// ---------------------------------------------------------------------------
// Kernel 1: gating, ONE THREAD per row. f32 sequential-k FMA dots (single
// accumulator per output, ascending k) to mirror the reference GEMM order.
// Weights staged in LDS (lane-uniform broadcast reads, conflict-free).
// ---------------------------------------------------------------------------
__global__ __launch_bounds__(256) void gating_kernel(
    const float* __restrict__ x, const float* __restrict__ gw,
    const float* __restrict__ nw, float* __restrict__ g_out,
    float* __restrict__ kept_out, float* __restrict__ ent_out) {
  __shared__ float s_gw[kE * kL];
  __shared__ float s_nw[kE * kL];
  for (int i = threadIdx.x; i < kE * kL; i += 256) {
    s_gw[i] = gw[i];
    s_nw[i] = nw[i];
  }
  __syncthreads();

  const int r = blockIdx.x * 256 + threadIdx.x;  // row id in [0, kRows)
  const float* xr = x + (size_t)r * kL;

  float accg[3] = {0.f, 0.f, 0.f};
  float accn[3] = {0.f, 0.f, 0.f};
  {
#pragma clang fp contract(off)
    for (int k0 = 0; k0 < kL; k0 += 16) {
      float xv[16];
      reinterpret_cast<float4*>(xv)[0] = *reinterpret_cast<const float4*>(xr + k0);
      reinterpret_cast<float4*>(xv)[1] = *reinterpret_cast<const float4*>(xr + k0 + 4);
      reinterpret_cast<float4*>(xv)[2] = *reinterpret_cast<const float4*>(xr + k0 + 8);
      reinterpret_cast<float4*>(xv)[3] = *reinterpret_cast<const float4*>(xr + k0 + 12);
#pragma unroll
      for (int q = 0; q < 16; ++q) {
        const float xq = xv[q];
        const int k = k0 + q;
        accg[0] = fmaf(xq, s_gw[0 * kL + k], accg[0]);
        accg[1] = fmaf(xq, s_gw[1 * kL + k], accg[1]);
        accg[2] = fmaf(xq, s_gw[2 * kL + k], accg[2]);
        accn[0] = fmaf(xq, s_nw[0 * kL + k], accn[0]);
        accn[1] = fmaf(xq, s_nw[1 * kL + k], accn[1]);
        accn[2] = fmaf(xq, s_nw[2 * kL + k], accn[2]);
      }
    }
  }

  {
#pragma clang fp contract(off)
    float noisy[3];
    const uint32_t nbase = (uint32_t)r * 3u;
#pragma unroll
    for (int e = 0; e < 3; ++e) {
      const float cl = accg[e];
      const float sp = softplus_f32(accn[e]) + 0.01f;  // NOISE_EPS
      const float nz = bits_to_normal(jax_random_bits(nbase + (uint32_t)e));
      const float prod = nz * sp;        // separate rounding: mul then add
      noisy[e] = cl + prod;
    }
    // softmax over 3 experts (f32, max-subtracted, as jax.nn.softmax)
    const float m = fmaxf(noisy[0], fmaxf(noisy[1], noisy[2]));
    float uu[3];
    uu[0] = expf(noisy[0] - m);
    uu[1] = expf(noisy[1] - m);
    uu[2] = expf(noisy[2] - m);
    const float ssum = (uu[0] + uu[1]) + uu[2];
    float p[3];
    p[0] = uu[0] / ssum;
    p[1] = uu[1] / ssum;
    p[2] = uu[2] / ssum;

    // stable descending argsort of 3 (ties -> lower original index first)
    int o0 = 0;
    if (p[1] > p[o0]) o0 = 1;
    if (p[2] > p[o0]) o0 = 2;
    const int i = (o0 == 0) ? 1 : 0;
    const int j = (o0 == 2) ? 1 : 2;
    const int o1 = (p[j] > p[i]) ? j : i;

    const float s0 = p[o0];
    const float s1 = p[o1];
    // cum > 0.5 top-p: keep top-1 iff s0 > 0.5, else top-2 (s0+s1 >= 2/3 always)
    const bool keep2 = !(s0 > 0.5f);

    float g[3] = {0.f, 0.f, 0.f};
    g[o0] = 1.f;
    if (keep2) g[o1] = 1.f;

    // entropy term: sum_e p * log(p + 1e-10)  (negated on store)
    float ent = 0.f;
    ent += p[0] * logf(p[0] + 1e-10f);
    ent += p[1] * logf(p[1] + 1e-10f);
    ent += p[2] * logf(p[2] + 1e-10f);

    const int bh = r >> 9;
    const int l = r & (kL - 1);
    g_out[r * 3 + 0] = g[0];
    g_out[r * 3 + 1] = g[1];
    g_out[r * 3 + 2] = g[2];
    // kept sorted probs, layout [jpos][l][bh] for coalesced bh-reduction
    kept_out[(0 * kL + l) * kBH + bh] = s0;
    kept_out[(1 * kL + l) * kBH + bh] = keep2 ? s1 : 0.f;
    kept_out[(2 * kL + l) * kBH + bh] = 0.f;
    ent_out[r] = -ent;
  }
}

// ---------------------------------------------------------------------------
// Kernel 2: deterministic loss reduction (single block).
// loss = var(importance, ddof=1)/(mean^2 + 1e-10) + 0.1 * ent_total/768
// ---------------------------------------------------------------------------
__global__ __launch_bounds__(1024) void loss_kernel(
    const float* __restrict__ kept, const float* __restrict__ ent,
    float* __restrict__ loss_out) {
  __shared__ double red[1024];
  __shared__ double imp[kL * kE];  // 1536 importance sums
  __shared__ double s_ent, s_mean;
  const int t = threadIdx.x;

  // total entropy (fixed-order tree -> deterministic)
  double a = 0.0;
  for (int idx = t; idx < kRows; idx += 1024) a += (double)ent[idx];
  red[t] = a;
  __syncthreads();
  for (int off = 512; off > 0; off >>= 1) {
    if (t < off) red[t] += red[t + off];
    __syncthreads();
  }
  if (t == 0) s_ent = red[0];
  __syncthreads();

  // importance[l, jpos] = sum over bh of kept (sequential per entry)
  for (int q = t; q < kL * kE; q += 1024) {
    const float* src = kept + (size_t)q * kBH;
    double s = 0.0;
    for (int b = 0; b < kBH; ++b) s += (double)src[b];
    imp[q] = s;
  }
  __syncthreads();

  // mean over 1536
  double v = imp[t] + ((t < kL * kE - 1024) ? imp[t + 1024] : 0.0);
  red[t] = v;
  __syncthreads();
  for (int off = 512; off > 0; off >>= 1) {
    if (t < off) red[t] += red[t + off];
    __syncthreads();
  }
  if (t == 0) s_mean = red[0] / (double)(kL * kE);
  __syncthreads();

  // variance (two-pass, ddof=1)
  double d0 = imp[t] - s_mean;
  double sq = d0 * d0;
  if (t < kL * kE - 1024) {
    double d1 = imp[t + 1024] - s_mean;
    sq += d1 * d1;
  }
  red[t] = sq;
  __syncthreads();
  for (int off = 512; off > 0; off >>= 1) {
    if (t < off) red[t] += red[t + off];
    __syncthreads();
  }
  if (t == 0) {
    const double var = red[0] / (double)(kL * kE - 1);
    const double loss_imp = var / (s_mean * s_mean + 1e-10);
    const double loss_dyn = s_ent / 768.0;  // sum(axis=1).mean() over [BH,E]
    loss_out[0] = (float)(loss_imp + 0.1 * loss_dyn);
  }
}

// ---------------------------------------------------------------------------
// Kernel 3: out[bh, l, d] = g[bh, l, cat(l,d)] + (l==d).
// cat: S if (d%64==l%64 && d!=l), T if (d/64==l/64), else ST. One block/row,
// 128 threads x float4 = 512 coalesced writes.
// ---------------------------------------------------------------------------
__global__ __launch_bounds__(128) void out_kernel(
    const float* __restrict__ g, float* __restrict__ out) {
  const int r = blockIdx.x;
  const int l = r & (kL - 1);
  const float g0 = g[r * 3 + 0];
  const float g1 = g[r * 3 + 1];
  const float g2 = g[r * 3 + 2];
  const int lblk = l >> 6;
  const int loff = l & 63;
  const int d0 = threadIdx.x * 4;
  float vals[4];
#pragma unroll
  for (int k = 0; k < 4; ++k) {
    const int d = d0 + k;
    float v;
    if (((d & 63) == loff) && (d != l)) v = g0;       // S
    else if ((d >> 6) == lblk) v = g1;                 // T (includes diagonal)
    else v = g2;                                       // ST
    if (d == l) v += 1.0f;                             // + eye
    vals[k] = v;
  }
  *reinterpret_cast<float4*>(out + (size_t)r * kL + d0) =
      *reinterpret_cast<float4*>(vals);
}

}  // namespace

extern "C" void kernel_launch(void* const* d_in, const int* in_sizes, int n_in,
                              void* d_out, int out_size, void* d_ws, size_t ws_size,
                              hipStream_t stream) {
  (void)in_sizes; (void)n_in; (void)out_size; (void)ws_size;
  const float* x = (const float*)d_in[0];       // [B,H,L,L] = [32,8,512,512]
  const float* gw = (const float*)d_in[1];      // [3,512]
  const float* nw = (const float*)d_in[2];      // [3,512]
  float* out = (float*)d_out;                   // 64M out + 1 loss

  float* ws = (float*)d_ws;
  float* ws_g = ws;                              // kRows*3 = 393216 floats
  float* ws_kept = ws + (size_t)kRows * 3;       // 393216 floats
  float* ws_ent = ws + (size_t)kRows * 6;        // 131072 floats

  gating_kernel<<<kRows / 256, 256, 0, stream>>>(x, gw, nw, ws_g, ws_kept, ws_ent);
  loss_kernel<<<1, 1024, 0, stream>>>(ws_kept, ws_ent, out + (size_t)kBH * kL * kL);
  out_kernel<<<kRows, 128, 0, stream>>>(ws_g, out);
}